// Round 10
// baseline (1460.358 us; speedup 1.0000x reference)
//
#include <hip/hip_runtime.h>
#include <math.h>

// B=512, N=128, E=256, H=8, D=32. All fp32 (argmax fidelity requires it).
//
// Round-16: make the R15 plan actually RUN. R15 post-mortem: counters showed
//  the fallback k_roll (LDS 157696) - use_qtab was 0 because qtab needed
//  ~269.5MB of ws and ws_size is ~256MiB. k_rollq (and R14's qtab pass!)
//  never executed.
//  Fix: qtab moves to a 64MiB __device__ static array (g_qtab) - no hipMalloc,
//  graph-capture-safe, referenced directly by k_gemm (writer) and k_rollq
//  (reader). ws keeps the proven layout; the gate and the fallback are gone.
//  Bit-exactness: k_gemm's qtab pass is the same sequential acc+=a*b over
//  g=0..255 then +qbase as the old in-kernel init (same TU/flags -> same fma
//  contraction; pk_fma is IEEE-exact per lane anyway).
//  Result: k_rollq LDS 17KB -> 2 blocks/CU, 4 waves/SIMD, ONE dispatch round.

#define B_ 512
#define N_ 128
#define E_ 256
#define H_ 8
#define D_ 32
#define NEG (-1.0e9f)
#define CLIPV 10.0f
#define SCALE 0.17677669529663688110f  /* 1/sqrt(32), fp32-rounded */

__device__ float g_qtab[(size_t)B_ * N_ * E_];   // 64 MiB static device memory

typedef float v2f __attribute__((ext_vector_type(2)));

// packed fp32 FMA: acc.lo += a.lo*b.lo; acc.hi += a.hi*b.hi  (one VALU instr)
__device__ __forceinline__ void pkfma(v2f& acc, v2f a, v2f b) {
  asm("v_pk_fma_f32 %0, %1, %2, %0" : "+v"(acc) : "v"(a), "v"(b));
}

// ---------------- wave-wide reductions (64 lanes), LDS-free ----------------
template <int CTRL>
__device__ __forceinline__ float dpp_f(float x) {
  int r = __builtin_amdgcn_update_dpp(__float_as_int(x), __float_as_int(x),
                                      CTRL, 0xf, 0xf, false);
  return __int_as_float(r);
}
template <int CTRL, int RM>
__device__ __forceinline__ float dpp_mv(float x, float idv) {
  int r = __builtin_amdgcn_update_dpp(__float_as_int(idv), __float_as_int(x),
                                      CTRL, RM, 0xf, false);
  return __int_as_float(r);
}
__device__ __forceinline__ float wred_max(float v) {
  v = fmaxf(v, dpp_f<0xB1>(v));                       // xor 1 (quad_perm)
  v = fmaxf(v, dpp_f<0x4E>(v));                       // xor 2 (quad_perm)
  v = fmaxf(v, dpp_f<0x124>(v));                      // row_ror:4
  v = fmaxf(v, dpp_f<0x128>(v));                      // row_ror:8 -> row totals
  v = fmaxf(v, dpp_mv<0x142, 0xa>(v, -1e38f));        // bcast15 -> rows 1,3
  v = fmaxf(v, dpp_mv<0x143, 0xc>(v, -1e38f));        // bcast31 -> rows 2,3
  return __int_as_float(__builtin_amdgcn_readlane(__float_as_int(v), 63));
}
__device__ __forceinline__ float wred_sum(float v) {
  v += dpp_f<0xB1>(v);
  v += dpp_f<0x4E>(v);
  v += dpp_f<0x124>(v);
  v += dpp_f<0x128>(v);
  v += dpp_mv<0x142, 0xa>(v, 0.0f);
  v += dpp_mv<0x143, 0xc>(v, 0.0f);
  return __int_as_float(__builtin_amdgcn_readlane(__float_as_int(v), 63));
}

// ---------------------------------------------------------------- K0: weight folds
__global__ void k0_prep(const float* __restrict__ Wqkv, const float* __restrict__ bqkv,
                        const float* __restrict__ Wmlp, const float* __restrict__ bmlp,
                        float* __restrict__ Wc, float* __restrict__ bc,
                        float* __restrict__ wc2, float* __restrict__ cconst) {
  int t = threadIdx.x;
  int blk = blockIdx.x;
  __shared__ float row_s[E_];
  if (blk < E_) {
    int g = blk;
    row_s[t] = Wqkv[g * 768 + 512 + t];
    __syncthreads();
    int f = t;
    const float4* wm4 = (const float4*)(Wmlp + f * E_);
    const float4* w34 = (const float4*)row_s;
    float acc = 0.f;
#pragma unroll 8
    for (int j = 0; j < E_ / 4; ++j) {
      float4 a = w34[j]; float4 bv = wm4[j];
      acc += a.x * bv.x + a.y * bv.y + a.z * bv.z + a.w * bv.w;
    }
    Wc[g * E_ + f] = acc;
  } else {
    int f = t;
    float a1 = 0.f, a2 = 0.f;
    for (int e = 0; e < E_; ++e) {
      a1 += bqkv[512 + e] * Wmlp[f * E_ + e];
      a2 += Wqkv[f * 768 + 512 + e] * bmlp[e];
    }
    bc[f] = a1;
    wc2[f] = a2;
    if (t == 0) {
      float c = 0.f;
      for (int e = 0; e < E_; ++e) c += bqkv[512 + e] * bmlp[e];
      *cconst = c;
    }
  }
}

// ---------------------------------------------------------------- K1: precompute GEMM (4 tensors)
__global__ __launch_bounds__(256, 2)
void k_gemm(const float* __restrict__ emb, const float* __restrict__ Wqkv,
            const float* __restrict__ bqkv,
            const float* __restrict__ Wc, const float* __restrict__ bc,
            const float* __restrict__ Wstep, const float* __restrict__ qbase,
            float* __restrict__ kk_, float* __restrict__ vv_,
            float* __restrict__ lk2, int ncc, int tmask) {
  __shared__ float As[256 * 64];  // [kk][m], exactly 64 KiB
  int t = threadIdx.x;
  int r0 = blockIdx.x * 64;
  {
    int m = t >> 2;
    int c0 = t & 3;
    const float4* e4 = (const float4*)emb;
#pragma unroll
    for (int p = 0; p < 16; ++p) {
      int c4 = c0 + p * 4;
      float4 a = e4[(size_t)(r0 + m) * 64 + c4];
      As[(c4 * 4 + 0) * 64 + m] = a.x;
      As[(c4 * 4 + 1) * 64 + m] = a.y;
      As[(c4 * 4 + 2) * 64 + m] = a.z;
      As[(c4 * 4 + 3) * 64 + m] = a.w;
    }
  }
  __syncthreads();
  int tx = t & 15, ty = t >> 4;
  const float4* As4 = (const float4*)As;
  for (int cc = 0; cc < ncc; ++cc) {
    const float* Bp; int ldb4; const float* bias; float* outp;
    int colbase = (cc & 1) * 128;
    switch (cc >> 1) {
      case 0:  Bp = Wqkv + colbase;          ldb4 = 192; bias = bqkv + colbase;       outp = kk_; break;
      case 1:  Bp = Wqkv + 256 + colbase;    ldb4 = 192; bias = bqkv + 256 + colbase; outp = vv_; break;
      case 2:  Bp = Wc + colbase;            ldb4 = 64;  bias = bc + colbase;         outp = lk2; break;
      default: Bp = Wstep + 65536 + colbase; ldb4 = 64;
               bias = qbase + (size_t)(r0 >> 7) * 256 + colbase;                      outp = g_qtab; break;
    }
    const float4* B4 = (const float4*)Bp;
    float acc[4][8];
#pragma unroll
    for (int i = 0; i < 4; ++i)
#pragma unroll
      for (int j = 0; j < 8; ++j) acc[i][j] = 0.f;

#pragma unroll 4
    for (int kk = 0; kk < 256; ++kk) {
      float4 b0 = B4[kk * ldb4 + tx * 2];
      float4 b1 = B4[kk * ldb4 + tx * 2 + 1];
      float4 av = As4[kk * 16 + ty];
      float a_[4] = {av.x, av.y, av.z, av.w};
#pragma unroll
      for (int i = 0; i < 4; ++i) {
        acc[i][0] += a_[i] * b0.x; acc[i][1] += a_[i] * b0.y;
        acc[i][2] += a_[i] * b0.z; acc[i][3] += a_[i] * b0.w;
        acc[i][4] += a_[i] * b1.x; acc[i][5] += a_[i] * b1.y;
        acc[i][6] += a_[i] * b1.z; acc[i][7] += a_[i] * b1.w;
      }
    }
    float bj[8];
#pragma unroll
    for (int j = 0; j < 8; ++j) bj[j] = bias ? bias[tx * 8 + j] : 0.f;
    int tr = (tmask >> (cc >> 1)) & 1;
    if (!tr) {
#pragma unroll
      for (int i = 0; i < 4; ++i) {
        int row = r0 + ty * 4 + i;
        float4 o0 = make_float4(acc[i][0] + bj[0], acc[i][1] + bj[1], acc[i][2] + bj[2], acc[i][3] + bj[3]);
        float4 o1 = make_float4(acc[i][4] + bj[4], acc[i][5] + bj[5], acc[i][6] + bj[6], acc[i][7] + bj[7]);
        float4* o4 = (float4*)(outp + (size_t)row * 256 + colbase + tx * 8);
        o4[0] = o0; o4[1] = o1;
      }
    } else {
#pragma unroll
      for (int i = 0; i < 4; ++i) {
        int row = r0 + ty * 4 + i;
        int bb = row >> 7, nn = row & 127;
        float* op = outp + (size_t)bb * 32768 + nn;
#pragma unroll
        for (int j = 0; j < 8; ++j)
          op[(size_t)(colbase + tx * 8 + j) * 128] = acc[i][j] + bj[j];
      }
    }
  }
}

// ---------------------------------------------------------------- K2: qbase per b
__global__ void k_qbase(const float* __restrict__ emb, const float* __restrict__ Wfix,
                        const float* __restrict__ bfix, const float* __restrict__ Wstep,
                        const float* __restrict__ bstep, float* __restrict__ qbase) {
  int b = blockIdx.x, t = threadIdx.x;
  __shared__ float ge[E_], fi[E_];
  const float* eb = emb + (size_t)b * N_ * E_;
  float s = 0.f;
#pragma unroll 8
  for (int n = 0; n < N_; ++n) s += eb[n * E_ + t];
  ge[t] = s * (1.0f / 128.0f);
  fi[t] = eb[t];
  __syncthreads();
  float acc = bfix[t] + bstep[t];
#pragma unroll 4
  for (int g = 0; g < E_; ++g)
    acc += ge[g] * Wfix[g * E_ + t] + fi[g] * Wstep[g * E_ + t];
  qbase[b * E_ + t] = acc;
}

// ---------------------------------------------------------------- K3: c[b,n]
__global__ void k_c(const float* __restrict__ emb, const float* __restrict__ wc2,
                    const float* __restrict__ cconst, float* __restrict__ cvec) {
  __shared__ float w[E_];
  int t = threadIdx.x;
  w[t] = wc2[t];
  __syncthreads();
  int row = blockIdx.x * 256 + t;
  const float4* e4 = (const float4*)(emb + (size_t)row * E_);
  const float4* w4 = (const float4*)w;
  float acc = 0.f;
#pragma unroll 8
  for (int j = 0; j < E_ / 4; ++j) {
    float4 a = e4[j], bv = w4[j];
    acc += a.x * bv.x + a.y * bv.y + a.z * bv.z + a.w * bv.w;
  }
  cvec[row] = acc + *cconst;
}

// ---------------------------------------------------------------- K4: rollout, q from g_qtab
// One block (512 thr, 8 waves) per b. LDS ~17KB -> 2 blocks/CU (4 waves/SIMD),
// one dispatch round. Loop arithmetic VERBATIM R14.
__global__ __launch_bounds__(512)
void k_rollq(const float* __restrict__ kT, const float* __restrict__ vv_,
             const float* __restrict__ lkT, const float* __restrict__ cvec,
             float* __restrict__ out) {
  int lt = threadIdx.x;
  int b = blockIdx.x;
  int h = lt >> 6;      // wave = head
  int j = lt & 63;      // lane

  __shared__ float work[4352];          // 17 KiB: at_s | ctx_s | zp
  float* at_s  = work;                  // [8][128] wave-private slices
  float* ctx_s = work + 1024;           // [8][32]  wave-private slices
  float* zp    = work + 1280;           // [2][128 rows x stride 12] z partials

  // ---- register fills as v2f pairs (coalesced within 32/64-lane groups) ----
  const float* kTb = kT + (size_t)b * 32768;
  const float* vb  = vv_ + (size_t)b * 32768;
  const float* lTb = lkT + (size_t)b * 32768;

  v2f k0p[16], k1p[16];       // k[h][2d..2d+1][j], k[h][..][j+64]
#pragma unroll
  for (int d = 0; d < 16; ++d) {
    k0p[d] = (v2f){kTb[(h * 32 + 2 * d) * 128 + j],      kTb[(h * 32 + 2 * d + 1) * 128 + j]};
    k1p[d] = (v2f){kTb[(h * 32 + 2 * d) * 128 + j + 64], kTb[(h * 32 + 2 * d + 1) * 128 + j + 64]};
    asm("" : "+v"(k0p[d]));
    asm("" : "+v"(k1p[d]));
  }
  int e_own = h * 32 + (j & 31), nh = j >> 5;
  v2f vp[32];                 // v[nh*64+2m..2m+1][e_own]
#pragma unroll
  for (int m = 0; m < 32; ++m) {
    vp[m] = (v2f){vb[(nh * 64 + 2 * m) * 256 + e_own], vb[(nh * 64 + 2 * m + 1) * 256 + e_own]};
    asm("" : "+v"(vp[m]));
  }
  v2f l0p[16], l1p[16];       // lk2[j][h-slice pairs], lk2[j+64][...]
#pragma unroll
  for (int e = 0; e < 16; ++e) {
    l0p[e] = (v2f){lTb[(h * 32 + 2 * e) * 128 + j],      lTb[(h * 32 + 2 * e + 1) * 128 + j]};
    l1p[e] = (v2f){lTb[(h * 32 + 2 * e) * 128 + j + 64], lTb[(h * 32 + 2 * e + 1) * 128 + j + 64]};
    asm("" : "+v"(l0p[e]));
    asm("" : "+v"(l1p[e]));
  }
  float cv_lo = cvec[b * 128 + j];
  float cv_hi = cvec[b * 128 + j + 64];
  int vis_lo = (j == 0) ? 1 : 0, vis_hi = 0;
  int cur = 0;
  float lp = 0.f;
  int rof0 = j * 12;
  int rof1 = rof0 + 768;      // (j+64)*12
  int csw  = h ^ ((j >> 2) & 7);
  const float* qhb = g_qtab + ((size_t)b << 15) + (h << 5);  // + cur*256 per step

#pragma unroll 1
  for (int it = 0; it < N_ - 1; ++it) {
    // --- scores (q row from g_qtab at wave-uniform address) ---
    int curu = __builtin_amdgcn_readfirstlane(cur);
    const float4* q4 = (const float4*)(qhb + (curu << 8));
    v2f s00 = {0.f, 0.f}, s01 = {0.f, 0.f}, s10 = {0.f, 0.f}, s11 = {0.f, 0.f};
#pragma unroll
    for (int dd = 0; dd < 8; ++dd) {
      float4 qv = q4[dd];
      v2f qa = {qv.x, qv.y}, qb = {qv.z, qv.w};
      pkfma(s00, qa, k0p[2 * dd]);
      pkfma(s01, qb, k0p[2 * dd + 1]);
      pkfma(s10, qa, k1p[2 * dd]);
      pkfma(s11, qb, k1p[2 * dd + 1]);
    }
    float slo = vis_lo ? NEG : ((s00.x + s00.y) + (s01.x + s01.y)) * SCALE;
    float shi = vis_hi ? NEG : ((s10.x + s10.y) + (s11.x + s11.y)) * SCALE;
    // --- softmax (in-wave; division deferred; DPP-only reductions) ---
    float m = wred_max(fmaxf(slo, shi));
    float elo = expf(slo - m), ehi = expf(shi - m);
    at_s[h * 128 + j] = elo;
    at_s[h * 128 + 64 + j] = ehi;
    float inv = 1.0f / wred_sum(elo + ehi);
    // --- ctx for e_own over n-half (wave-local LDS read, no barrier) ---
    const float4* a4 = (const float4*)(at_s + h * 128 + nh * 64);
    v2f c0 = {0.f, 0.f}, c1 = {0.f, 0.f};
#pragma unroll
    for (int mm = 0; mm < 16; ++mm) {
      float4 av = a4[mm];
      v2f aa = {av.x, av.y}, ab = {av.z, av.w};
      pkfma(c0, aa, vp[2 * mm]);
      pkfma(c1, ab, vp[2 * mm + 1]);
    }
    float c = (c0.x + c0.y) + (c1.x + c1.y);
    c += __shfl_xor(c, 32);     // combine n-halves (lanes j, j^32 share e_own)
    c *= inv;
    if (j < 32) ctx_s[h * 32 + j] = c;
    // --- z partial for head-slice (wave-local broadcast read) ---
    const float4* cx4 = (const float4*)(ctx_s + h * 32);
    v2f z00 = {0.f, 0.f}, z01 = {0.f, 0.f}, z10 = {0.f, 0.f}, z11 = {0.f, 0.f};
#pragma unroll
    for (int ee = 0; ee < 8; ++ee) {
      float4 cv = cx4[ee];
      v2f ca = {cv.x, cv.y}, cb = {cv.z, cv.w};
      pkfma(z00, ca, l0p[2 * ee]);
      pkfma(z01, cb, l0p[2 * ee + 1]);
      pkfma(z10, ca, l1p[2 * ee]);
      pkfma(z11, cb, l1p[2 * ee + 1]);
    }
    float* zpw = zp + (it & 1) * 1536;
    zpw[rof0 + csw] = (z00.x + z00.y) + (z01.x + z01.y);
    zpw[rof1 + csw] = (z10.x + z10.y) + (z11.x + z11.y);
    __syncthreads();   // the ONLY barrier per step

    // --- phase C: assemble z via 2x b128/half + argmax; LSE wave 0 only ---
    const float4* zr0 = (const float4*)(zpw + rof0);
    const float4* zr1 = (const float4*)(zpw + rof1);
    float4 za = zr0[0], zb = zr0[1], zc = zr1[0], zd = zr1[1];
    float zlo = cv_lo + ((za.x + za.y) + (za.z + za.w)) + ((zb.x + zb.y) + (zb.z + zb.w));
    float zhi = cv_hi + ((zc.x + zc.y) + (zc.z + zc.w)) + ((zd.x + zd.y) + (zd.z + zd.w));
    float zmlo = vis_lo ? -1e30f : zlo;
    float zmhi = vis_hi ? -1e30f : zhi;
    float vmax = wred_max(fmaxf(zmlo, zmhi));
    unsigned long long blo = __ballot(zmlo == vmax);
    int action;
    if (blo) action = __ffsll((unsigned long long)blo) - 1;
    else     action = 63 + __ffsll((unsigned long long)__ballot(zmhi == vmax));
    if (h == 0) {
      float lmax = CLIPV * tanhf(vmax * SCALE);
      float tlo = vis_lo ? 0.f : expf(CLIPV * tanhf(zlo * SCALE) - 10.0f);
      float thi = vis_hi ? 0.f : expf(CLIPV * tanhf(zhi * SCALE) - 10.0f);
      float S = wred_sum(tlo + thi);
      lp += lmax - 10.0f - logf(S);
    }
    cur = action;
    vis_lo |= (action == j);
    vis_hi |= (action == j + 64);
  }
  if (lt == 0) out[b] = lp;
}

// ---------------------------------------------------------------- launch
extern "C" void kernel_launch(void* const* d_in, const int* in_sizes, int n_in,
                              void* d_out, int out_size, void* d_ws, size_t ws_size,
                              hipStream_t stream) {
  (void)in_sizes; (void)n_in; (void)out_size; (void)ws_size;
  const float* emb   = (const float*)d_in[0];
  const float* Wqkv  = (const float*)d_in[1];
  const float* bqkv  = (const float*)d_in[2];
  const float* Wfix  = (const float*)d_in[3];
  const float* bfix  = (const float*)d_in[4];
  const float* Wstep = (const float*)d_in[5];
  const float* bstep = (const float*)d_in[6];
  const float* Wmlp  = (const float*)d_in[7];
  const float* bmlp  = (const float*)d_in[8];
  float* out = (float*)d_out;
  float* ws = (float*)d_ws;

  const size_t NBE = (size_t)B_ * N_ * E_;  // 16,777,216 floats
  float* kk_    = ws;                  // kT
  float* vv_    = ws + NBE;            // v
  float* lk2    = ws + 2 * NBE;        // lkT
  float* qbase  = ws + 3 * NBE;        // 131072
  float* cvec   = qbase + 131072;      // 65536
  float* Wc     = cvec + 65536;        // 65536
  float* bc     = Wc + 65536;          // 256
  float* wc2    = bc + 256;            // 256
  float* cconst = wc2 + 256;           // (64 pad)

  hipLaunchKernelGGL(k0_prep, dim3(257), dim3(256), 0, stream,
                     Wqkv, bqkv, Wmlp, bmlp, Wc, bc, wc2, cconst);
  hipLaunchKernelGGL(k_qbase, dim3(512), dim3(256), 0, stream,
                     emb, Wfix, bfix, Wstep, bstep, qbase);
  hipLaunchKernelGGL(k_c, dim3(256), dim3(256), 0, stream,
                     emb, wc2, cconst, cvec);
  hipLaunchKernelGGL(k_gemm, dim3(1024), dim3(256), 0, stream,
                     emb, Wqkv, bqkv, Wc, bc, Wstep, qbase,
                     kk_, vv_, lk2, 8, 0b0101);
  hipLaunchKernelGGL(k_rollq, dim3(512), dim3(512), 0, stream,
                     kk_, vv_, lk2, cvec, out);
}

// Round 11
// 1132.820 us; speedup vs baseline: 1.2891x; 1.2891x over previous
//
#include <hip/hip_runtime.h>
#include <math.h>

// B=512, N=128, E=256, H=8, D=32. All fp32 (argmax fidelity requires it).
//
// Round-17: revert to R14 (best passing: 1165us, k_roll 604 / k_gemm ~520) and
//  attack k_gemm, which R16 exposed as ~520us (per-pass ~87us x 6).
//  R16 post-mortem: qtab-hoist cost k_gemm +175us to save k_roll ~50us (net
//  loss), and k_rollq's doubled occupancy was eaten by per-step qtab L3/HBM
//  latency on the serial chain (one round @2blk/CU ~= two rounds @1blk/CU).
//  -> q stays in LDS; occupancy is not the k_roll lever.
//  ONE change vs R14: k_gemm inner loop packs the 32 scalar v_fmac into 16
//  v_pk_fma_f32 (R11 proved pk_fma issues at scalar-fma rate on this chip).
//  Bit-exact: each acc chain becomes one v2f component - same IEEE fma, same
//  kk order, same epilogue -> identical bits, absmax 0.0.

#define B_ 512
#define N_ 128
#define E_ 256
#define H_ 8
#define D_ 32
#define NEG (-1.0e9f)
#define CLIPV 10.0f
#define SCALE 0.17677669529663688110f  /* 1/sqrt(32), fp32-rounded */

typedef float v2f __attribute__((ext_vector_type(2)));

// packed fp32 FMA: acc.lo += a.lo*b.lo; acc.hi += a.hi*b.hi  (one VALU instr)
__device__ __forceinline__ void pkfma(v2f& acc, v2f a, v2f b) {
  asm("v_pk_fma_f32 %0, %1, %2, %0" : "+v"(acc) : "v"(a), "v"(b));
}

// ---------------- wave-wide reductions (64 lanes), LDS-free ----------------
template <int CTRL>
__device__ __forceinline__ float dpp_f(float x) {
  int r = __builtin_amdgcn_update_dpp(__float_as_int(x), __float_as_int(x),
                                      CTRL, 0xf, 0xf, false);
  return __int_as_float(r);
}
template <int CTRL, int RM>
__device__ __forceinline__ float dpp_mv(float x, float idv) {
  int r = __builtin_amdgcn_update_dpp(__float_as_int(idv), __float_as_int(x),
                                      CTRL, RM, 0xf, false);
  return __int_as_float(r);
}
__device__ __forceinline__ float wred_max(float v) {
  v = fmaxf(v, dpp_f<0xB1>(v));                       // xor 1 (quad_perm)
  v = fmaxf(v, dpp_f<0x4E>(v));                       // xor 2 (quad_perm)
  v = fmaxf(v, dpp_f<0x124>(v));                      // row_ror:4
  v = fmaxf(v, dpp_f<0x128>(v));                      // row_ror:8 -> row totals
  v = fmaxf(v, dpp_mv<0x142, 0xa>(v, -1e38f));        // bcast15 -> rows 1,3
  v = fmaxf(v, dpp_mv<0x143, 0xc>(v, -1e38f));        // bcast31 -> rows 2,3
  return __int_as_float(__builtin_amdgcn_readlane(__float_as_int(v), 63));
}
__device__ __forceinline__ float wred_sum(float v) {
  v += dpp_f<0xB1>(v);
  v += dpp_f<0x4E>(v);
  v += dpp_f<0x124>(v);
  v += dpp_f<0x128>(v);
  v += dpp_mv<0x142, 0xa>(v, 0.0f);
  v += dpp_mv<0x143, 0xc>(v, 0.0f);
  return __int_as_float(__builtin_amdgcn_readlane(__float_as_int(v), 63));
}

// ---------------------------------------------------------------- K0: weight folds
__global__ void k0_prep(const float* __restrict__ Wqkv, const float* __restrict__ bqkv,
                        const float* __restrict__ Wmlp, const float* __restrict__ bmlp,
                        float* __restrict__ Wc, float* __restrict__ bc,
                        float* __restrict__ wc2, float* __restrict__ cconst) {
  int t = threadIdx.x;
  int blk = blockIdx.x;
  __shared__ float row_s[E_];
  if (blk < E_) {
    int g = blk;
    row_s[t] = Wqkv[g * 768 + 512 + t];
    __syncthreads();
    int f = t;
    const float4* wm4 = (const float4*)(Wmlp + f * E_);
    const float4* w34 = (const float4*)row_s;
    float acc = 0.f;
#pragma unroll 8
    for (int j = 0; j < E_ / 4; ++j) {
      float4 a = w34[j]; float4 bv = wm4[j];
      acc += a.x * bv.x + a.y * bv.y + a.z * bv.z + a.w * bv.w;
    }
    Wc[g * E_ + f] = acc;
  } else {
    int f = t;
    float a1 = 0.f, a2 = 0.f;
    for (int e = 0; e < E_; ++e) {
      a1 += bqkv[512 + e] * Wmlp[f * E_ + e];
      a2 += Wqkv[f * 768 + 512 + e] * bmlp[e];
    }
    bc[f] = a1;
    wc2[f] = a2;
    if (t == 0) {
      float c = 0.f;
      for (int e = 0; e < E_; ++e) c += bqkv[512 + e] * bmlp[e];
      *cconst = c;
    }
  }
}

// ---------------------------------------------------------------- K1: precompute GEMM (3 tensors)
__global__ __launch_bounds__(256, 2)
void k_gemm(const float* __restrict__ emb, const float* __restrict__ Wqkv,
            const float* __restrict__ bqkv,
            const float* __restrict__ Wc, const float* __restrict__ bc,
            float* __restrict__ kk_, float* __restrict__ vv_,
            float* __restrict__ lk2, int ncc, int tmask) {
  __shared__ float As[256 * 64];  // [kk][m], exactly 64 KiB
  int t = threadIdx.x;
  int r0 = blockIdx.x * 64;
  {
    int m = t >> 2;
    int c0 = t & 3;
    const float4* e4 = (const float4*)emb;
#pragma unroll
    for (int p = 0; p < 16; ++p) {
      int c4 = c0 + p * 4;
      float4 a = e4[(size_t)(r0 + m) * 64 + c4];
      As[(c4 * 4 + 0) * 64 + m] = a.x;
      As[(c4 * 4 + 1) * 64 + m] = a.y;
      As[(c4 * 4 + 2) * 64 + m] = a.z;
      As[(c4 * 4 + 3) * 64 + m] = a.w;
    }
  }
  __syncthreads();
  int tx = t & 15, ty = t >> 4;
  const float4* As4 = (const float4*)As;
  for (int cc = 0; cc < ncc; ++cc) {
    const float* Bp; int ldb4; const float* bias; float* outp;
    int colbase = (cc & 1) * 128;
    switch (cc >> 1) {
      case 0:  Bp = Wqkv + colbase;          ldb4 = 192; bias = bqkv + colbase;       outp = kk_; break;
      case 1:  Bp = Wqkv + 256 + colbase;    ldb4 = 192; bias = bqkv + 256 + colbase; outp = vv_; break;
      default: Bp = Wc + colbase;            ldb4 = 64;  bias = bc + colbase;         outp = lk2; break;
    }
    const float4* B4 = (const float4*)Bp;
    // v2f accumulators: acc[i][jp] components = old scalar acc[i][2*jp+0/1].
    // Same fma op, same kk order per component -> bit-identical to R14.
    v2f acc[4][4];
#pragma unroll
    for (int i = 0; i < 4; ++i)
#pragma unroll
      for (int jp = 0; jp < 4; ++jp) acc[i][jp] = (v2f){0.f, 0.f};

#pragma unroll 4
    for (int kk = 0; kk < 256; ++kk) {
      float4 b0 = B4[kk * ldb4 + tx * 2];
      float4 b1 = B4[kk * ldb4 + tx * 2 + 1];
      v2f bp0 = {b0.x, b0.y}, bp1 = {b0.z, b0.w};
      v2f bp2 = {b1.x, b1.y}, bp3 = {b1.z, b1.w};
      float4 av = As4[kk * 16 + ty];
      float a_[4] = {av.x, av.y, av.z, av.w};
#pragma unroll
      for (int i = 0; i < 4; ++i) {
        v2f aa = {a_[i], a_[i]};
        pkfma(acc[i][0], aa, bp0);
        pkfma(acc[i][1], aa, bp1);
        pkfma(acc[i][2], aa, bp2);
        pkfma(acc[i][3], aa, bp3);
      }
    }
    float bj[8];
#pragma unroll
    for (int j = 0; j < 8; ++j) bj[j] = bias ? bias[tx * 8 + j] : 0.f;
    int tr = (tmask >> (cc >> 1)) & 1;
    if (!tr) {
#pragma unroll
      for (int i = 0; i < 4; ++i) {
        int row = r0 + ty * 4 + i;
        float4 o0 = make_float4(acc[i][0][0] + bj[0], acc[i][0][1] + bj[1],
                                acc[i][1][0] + bj[2], acc[i][1][1] + bj[3]);
        float4 o1 = make_float4(acc[i][2][0] + bj[4], acc[i][2][1] + bj[5],
                                acc[i][3][0] + bj[6], acc[i][3][1] + bj[7]);
        float4* o4 = (float4*)(outp + (size_t)row * 256 + colbase + tx * 8);
        o4[0] = o0; o4[1] = o1;
      }
    } else {
#pragma unroll
      for (int i = 0; i < 4; ++i) {
        int row = r0 + ty * 4 + i;
        int bb = row >> 7, nn = row & 127;
        float* op = outp + (size_t)bb * 32768 + nn;
#pragma unroll
        for (int j = 0; j < 8; ++j)
          op[(size_t)(colbase + tx * 8 + j) * 128] = acc[i][j >> 1][j & 1] + bj[j];
      }
    }
  }
}

// ---------------------------------------------------------------- K2: qbase per b
__global__ void k_qbase(const float* __restrict__ emb, const float* __restrict__ Wfix,
                        const float* __restrict__ bfix, const float* __restrict__ Wstep,
                        const float* __restrict__ bstep, float* __restrict__ qbase) {
  int b = blockIdx.x, t = threadIdx.x;
  __shared__ float ge[E_], fi[E_];
  const float* eb = emb + (size_t)b * N_ * E_;
  float s = 0.f;
#pragma unroll 8
  for (int n = 0; n < N_; ++n) s += eb[n * E_ + t];
  ge[t] = s * (1.0f / 128.0f);
  fi[t] = eb[t];
  __syncthreads();
  float acc = bfix[t] + bstep[t];
#pragma unroll 4
  for (int g = 0; g < E_; ++g)
    acc += ge[g] * Wfix[g * E_ + t] + fi[g] * Wstep[g * E_ + t];
  qbase[b * E_ + t] = acc;
}

// ---------------------------------------------------------------- K3: c[b,n]
__global__ void k_c(const float* __restrict__ emb, const float* __restrict__ wc2,
                    const float* __restrict__ cconst, float* __restrict__ cvec) {
  __shared__ float w[E_];
  int t = threadIdx.x;
  w[t] = wc2[t];
  __syncthreads();
  int row = blockIdx.x * 256 + t;
  const float4* e4 = (const float4*)(emb + (size_t)row * E_);
  const float4* w4 = (const float4*)w;
  float acc = 0.f;
#pragma unroll 8
  for (int j = 0; j < E_ / 4; ++j) {
    float4 a = e4[j], bv = w4[j];
    acc += a.x * bv.x + a.y * bv.y + a.z * bv.z + a.w * bv.w;
  }
  cvec[row] = acc + *cconst;
}

// ---------------------------------------------------------------- K4: wave-per-head rollout (verbatim R14)
__global__ __attribute__((amdgpu_flat_work_group_size(512, 512), amdgpu_waves_per_eu(2, 2)))
void k_roll(const float* __restrict__ emb, const float* __restrict__ Wstep,
            const float* __restrict__ kT, const float* __restrict__ vv_,
            const float* __restrict__ lkT,
            const float* __restrict__ qbase, const float* __restrict__ cvec,
            float* __restrict__ out) {
  int lt = threadIdx.x;
  int b = blockIdx.x;
  int h = lt >> 6;      // wave = head
  int j = lt & 63;      // lane

  __shared__ float sq_lds[128 * 260];   // 130 KiB (stride 260: store bank spread)
  __shared__ float work[6144];          // 24 KiB overlay: init At/Bs | at_s/ctx_s/zp
  float* at_s  = work;                  // [8][128] wave-private slices
  float* ctx_s = work + 1024;           // [8][32]  wave-private slices
  float* zp    = work + 1280;           // [2][128 rows x stride 12] z partials

  {
    // ---- init: sq_lds[n][e] = qbase[b][e] + emb[b][n] @ Wstep2 ----
    float* At = work;           // [16][128]
    float* Bs = work + 2048;    // [16][256]
    const float4* eb4 = (const float4*)(emb + (size_t)b * 32768);
    const float* W2 = Wstep + 65536;
    int n0 = (lt & 31) * 4;
    int e0 = (lt >> 5) * 16;
    float acc[4][16];
#pragma unroll
    for (int i = 0; i < 4; ++i)
#pragma unroll
      for (int jj = 0; jj < 16; ++jj) acc[i][jj] = 0.f;

    for (int gc = 0; gc < 16; ++gc) {
      {
        int n = lt & 127, q4g = lt >> 7;
        float4 a = eb4[n * 64 + gc * 4 + q4g];
        At[(q4g * 4 + 0) * 128 + n] = a.x;
        At[(q4g * 4 + 1) * 128 + n] = a.y;
        At[(q4g * 4 + 2) * 128 + n] = a.z;
        At[(q4g * 4 + 3) * 128 + n] = a.w;
      }
      {
        const float4* w4 = (const float4*)(W2 + gc * 16 * 256);
        ((float4*)Bs)[lt] = w4[lt];
        ((float4*)Bs)[lt + 512] = w4[lt + 512];
      }
      __syncthreads();
#pragma unroll
      for (int gi = 0; gi < 16; ++gi) {
        float4 a4 = *(const float4*)(At + gi * 128 + n0);
        const float4* bp = (const float4*)(Bs + gi * 256 + e0);
        float4 b0 = bp[0], b1 = bp[1], b2 = bp[2], b3 = bp[3];
        float av[4] = {a4.x, a4.y, a4.z, a4.w};
        float bv[16] = {b0.x, b0.y, b0.z, b0.w, b1.x, b1.y, b1.z, b1.w,
                        b2.x, b2.y, b2.z, b2.w, b3.x, b3.y, b3.z, b3.w};
#pragma unroll
        for (int i = 0; i < 4; ++i)
#pragma unroll
          for (int jj = 0; jj < 16; ++jj) acc[i][jj] += av[i] * bv[jj];
      }
      __syncthreads();
    }
    const float* qb = qbase + (size_t)b * 256;
    float qbr[16];
#pragma unroll
    for (int jj = 0; jj < 16; ++jj) qbr[jj] = qb[e0 + jj];
#pragma unroll
    for (int i = 0; i < 4; ++i)
#pragma unroll
      for (int jj = 0; jj < 16; ++jj)
        sq_lds[(n0 + i) * 260 + e0 + jj] = acc[i][jj] + qbr[jj];
  }
  __syncthreads();
  __builtin_amdgcn_sched_barrier(0);

  // ---- register fills as v2f pairs (coalesced within 32/64-lane groups) ----
  const float* kTb = kT + (size_t)b * 32768;
  const float* vb  = vv_ + (size_t)b * 32768;
  const float* lTb = lkT + (size_t)b * 32768;

  v2f k0p[16], k1p[16];       // k[h][2d..2d+1][j], k[h][..][j+64]
#pragma unroll
  for (int d = 0; d < 16; ++d) {
    k0p[d] = (v2f){kTb[(h * 32 + 2 * d) * 128 + j],      kTb[(h * 32 + 2 * d + 1) * 128 + j]};
    k1p[d] = (v2f){kTb[(h * 32 + 2 * d) * 128 + j + 64], kTb[(h * 32 + 2 * d + 1) * 128 + j + 64]};
    asm("" : "+v"(k0p[d]));
    asm("" : "+v"(k1p[d]));
  }
  int e_own = h * 32 + (j & 31), nh = j >> 5;
  v2f vp[32];                 // v[nh*64+2m..2m+1][e_own]
#pragma unroll
  for (int m = 0; m < 32; ++m) {
    vp[m] = (v2f){vb[(nh * 64 + 2 * m) * 256 + e_own], vb[(nh * 64 + 2 * m + 1) * 256 + e_own]};
    asm("" : "+v"(vp[m]));
  }
  v2f l0p[16], l1p[16];       // lk2[j][h-slice pairs], lk2[j+64][...]
#pragma unroll
  for (int e = 0; e < 16; ++e) {
    l0p[e] = (v2f){lTb[(h * 32 + 2 * e) * 128 + j],      lTb[(h * 32 + 2 * e + 1) * 128 + j]};
    l1p[e] = (v2f){lTb[(h * 32 + 2 * e) * 128 + j + 64], lTb[(h * 32 + 2 * e + 1) * 128 + j + 64]};
    asm("" : "+v"(l0p[e]));
    asm("" : "+v"(l1p[e]));
  }
  float cv_lo = cvec[b * 128 + j];
  float cv_hi = cvec[b * 128 + j + 64];
  int vis_lo = (j == 0) ? 1 : 0, vis_hi = 0;
  int cur = 0;
  float lp = 0.f;
  int rof0 = j * 12;
  int rof1 = rof0 + 768;      // (j+64)*12
  int csw  = h ^ ((j >> 2) & 7);

#pragma unroll 1
  for (int it = 0; it < N_ - 1; ++it) {
    // --- scores (wave-local; q row broadcast-read from sq_lds) ---
    const float4* q4 = (const float4*)(sq_lds + cur * 260 + h * 32);
    v2f s00 = {0.f, 0.f}, s01 = {0.f, 0.f}, s10 = {0.f, 0.f}, s11 = {0.f, 0.f};
#pragma unroll
    for (int dd = 0; dd < 8; ++dd) {
      float4 qv = q4[dd];
      v2f qa = {qv.x, qv.y}, qb = {qv.z, qv.w};
      pkfma(s00, qa, k0p[2 * dd]);
      pkfma(s01, qb, k0p[2 * dd + 1]);
      pkfma(s10, qa, k1p[2 * dd]);
      pkfma(s11, qb, k1p[2 * dd + 1]);
    }
    float slo = vis_lo ? NEG : ((s00.x + s00.y) + (s01.x + s01.y)) * SCALE;
    float shi = vis_hi ? NEG : ((s10.x + s10.y) + (s11.x + s11.y)) * SCALE;
    // --- softmax (in-wave; division deferred; DPP-only reductions) ---
    float m = wred_max(fmaxf(slo, shi));
    float elo = expf(slo - m), ehi = expf(shi - m);
    at_s[h * 128 + j] = elo;
    at_s[h * 128 + 64 + j] = ehi;
    float inv = 1.0f / wred_sum(elo + ehi);
    // --- ctx for e_own over n-half (wave-local LDS read, no barrier) ---
    const float4* a4 = (const float4*)(at_s + h * 128 + nh * 64);
    v2f c0 = {0.f, 0.f}, c1 = {0.f, 0.f};
#pragma unroll
    for (int mm = 0; mm < 16; ++mm) {
      float4 av = a4[mm];
      v2f aa = {av.x, av.y}, ab = {av.z, av.w};
      pkfma(c0, aa, vp[2 * mm]);
      pkfma(c1, ab, vp[2 * mm + 1]);
    }
    float c = (c0.x + c0.y) + (c1.x + c1.y);
    c += __shfl_xor(c, 32);     // combine n-halves (lanes j, j^32 share e_own)
    c *= inv;
    if (j < 32) ctx_s[h * 32 + j] = c;
    // --- z partial for head-slice (wave-local broadcast read) ---
    const float4* cx4 = (const float4*)(ctx_s + h * 32);
    v2f z00 = {0.f, 0.f}, z01 = {0.f, 0.f}, z10 = {0.f, 0.f}, z11 = {0.f, 0.f};
#pragma unroll
    for (int ee = 0; ee < 8; ++ee) {
      float4 cv = cx4[ee];
      v2f ca = {cv.x, cv.y}, cb = {cv.z, cv.w};
      pkfma(z00, ca, l0p[2 * ee]);
      pkfma(z01, cb, l0p[2 * ee + 1]);
      pkfma(z10, ca, l1p[2 * ee]);
      pkfma(z11, cb, l1p[2 * ee + 1]);
    }
    float* zpw = zp + (it & 1) * 1536;
    zpw[rof0 + csw] = (z00.x + z00.y) + (z01.x + z01.y);
    zpw[rof1 + csw] = (z10.x + z10.y) + (z11.x + z11.y);
    __syncthreads();   // the ONLY barrier per step

    // --- phase C: assemble z via 2x b128/half + argmax; LSE wave 0 only ---
    const float4* zr0 = (const float4*)(zpw + rof0);
    const float4* zr1 = (const float4*)(zpw + rof1);
    float4 za = zr0[0], zb = zr0[1], zc = zr1[0], zd = zr1[1];
    float zlo = cv_lo + ((za.x + za.y) + (za.z + za.w)) + ((zb.x + zb.y) + (zb.z + zb.w));
    float zhi = cv_hi + ((zc.x + zc.y) + (zc.z + zc.w)) + ((zd.x + zd.y) + (zd.z + zd.w));
    float zmlo = vis_lo ? -1e30f : zlo;
    float zmhi = vis_hi ? -1e30f : zhi;
    float vmax = wred_max(fmaxf(zmlo, zmhi));
    unsigned long long blo = __ballot(zmlo == vmax);
    int action;
    if (blo) action = __ffsll((unsigned long long)blo) - 1;
    else     action = 63 + __ffsll((unsigned long long)__ballot(zmhi == vmax));
    if (h == 0) {
      float lmax = CLIPV * tanhf(vmax * SCALE);
      float tlo = vis_lo ? 0.f : expf(CLIPV * tanhf(zlo * SCALE) - 10.0f);
      float thi = vis_hi ? 0.f : expf(CLIPV * tanhf(zhi * SCALE) - 10.0f);
      float S = wred_sum(tlo + thi);
      lp += lmax - 10.0f - logf(S);
    }
    cur = action;
    vis_lo |= (action == j);
    vis_hi |= (action == j + 64);
  }
  if (lt == 0) out[b] = lp;
}

// ---------------------------------------------------------------- launch
extern "C" void kernel_launch(void* const* d_in, const int* in_sizes, int n_in,
                              void* d_out, int out_size, void* d_ws, size_t ws_size,
                              hipStream_t stream) {
  (void)in_sizes; (void)n_in; (void)out_size; (void)ws_size;
  const float* emb   = (const float*)d_in[0];
  const float* Wqkv  = (const float*)d_in[1];
  const float* bqkv  = (const float*)d_in[2];
  const float* Wfix  = (const float*)d_in[3];
  const float* bfix  = (const float*)d_in[4];
  const float* Wstep = (const float*)d_in[5];
  const float* bstep = (const float*)d_in[6];
  const float* Wmlp  = (const float*)d_in[7];
  const float* bmlp  = (const float*)d_in[8];
  float* out = (float*)d_out;
  float* ws = (float*)d_ws;

  const size_t NBE = (size_t)B_ * N_ * E_;  // 16,777,216 floats
  float* kk_    = ws;                  // kT
  float* vv_    = ws + NBE;            // v
  float* lk2    = ws + 2 * NBE;        // lkT
  float* qbase  = ws + 3 * NBE;        // 131072
  float* cvec   = qbase + 131072;      // 65536
  float* Wc     = cvec + 65536;        // 65536
  float* bc     = Wc + 65536;          // 256
  float* wc2    = bc + 256;            // 256
  float* cconst = wc2 + 256;           // (64 pad)

  hipLaunchKernelGGL(k0_prep, dim3(257), dim3(256), 0, stream,
                     Wqkv, bqkv, Wmlp, bmlp, Wc, bc, wc2, cconst);
  hipLaunchKernelGGL(k_qbase, dim3(512), dim3(256), 0, stream,
                     emb, Wfix, bfix, Wstep, bstep, qbase);
  hipLaunchKernelGGL(k_c, dim3(256), dim3(256), 0, stream,
                     emb, wc2, cconst, cvec);
  hipLaunchKernelGGL(k_gemm, dim3(1024), dim3(256), 0, stream,
                     emb, Wqkv, bqkv, Wc, bc, kk_, vv_, lk2, 6, 0b101);
  hipLaunchKernelGGL(k_roll, dim3(512), dim3(512), 0, stream,
                     emb, Wstep, kk_, vv_, lk2, qbase, cvec, out);
}

// Round 12
// 1132.120 us; speedup vs baseline: 1.2899x; 1.0006x over previous
//
#include <hip/hip_runtime.h>
#include <math.h>

// B=512, N=128, E=256, H=8, D=32. All fp32 (argmax fidelity requires it).
//
// Round-18 (on R17's 1133us = k_roll 604 + k_gemm ~480 + small ~50):
//  k_gemm-only, both changes bit-exact (same fma sequence per output):
//   1. op_sel broadcast in v_pk_fma_f32 (op_sel/op_sel_hi on src0) - the
//      scalar a is broadcast inside the instruction, killing the 8 v_mov
//      pair-constructions/kk that R17's plain pkfma needed.
//   2. Fuse each tensor's two colbase halves into ONE kk loop (6 cc -> 3):
//      per kk 1 As read + 4 B loads + 32 pkfma (was 2 As reads + loop
//      overhead x2). acc 64 floats (~120 VGPR, fine at launch_bounds(256,2)
//      -> 256/wave budget); unroll 2 to cap register peaks.
//  k_roll verbatim R14/R17 (chain-latency-bound; no safe lever this round).

#define B_ 512
#define N_ 128
#define E_ 256
#define H_ 8
#define D_ 32
#define NEG (-1.0e9f)
#define CLIPV 10.0f
#define SCALE 0.17677669529663688110f  /* 1/sqrt(32), fp32-rounded */

typedef float v2f __attribute__((ext_vector_type(2)));

// packed fp32 FMA: acc.lo += a.lo*b.lo; acc.hi += a.hi*b.hi  (one VALU instr)
__device__ __forceinline__ void pkfma(v2f& acc, v2f a, v2f b) {
  asm("v_pk_fma_f32 %0, %1, %2, %0" : "+v"(acc) : "v"(a), "v"(b));
}
// broadcast WORD0 of the a-pair into both lanes (no movs): lo<-w0, hi<-w0
__device__ __forceinline__ void pkfma_bl(v2f& acc, v2f a, v2f b) {
  asm("v_pk_fma_f32 %0, %1, %2, %0 op_sel:[0,0,0] op_sel_hi:[0,1,1]"
      : "+v"(acc) : "v"(a), "v"(b));
}
// broadcast WORD1 of the a-pair into both lanes: lo<-w1, hi<-w1
__device__ __forceinline__ void pkfma_bh(v2f& acc, v2f a, v2f b) {
  asm("v_pk_fma_f32 %0, %1, %2, %0 op_sel:[1,0,0] op_sel_hi:[1,1,1]"
      : "+v"(acc) : "v"(a), "v"(b));
}

// ---------------- wave-wide reductions (64 lanes), LDS-free ----------------
template <int CTRL>
__device__ __forceinline__ float dpp_f(float x) {
  int r = __builtin_amdgcn_update_dpp(__float_as_int(x), __float_as_int(x),
                                      CTRL, 0xf, 0xf, false);
  return __int_as_float(r);
}
template <int CTRL, int RM>
__device__ __forceinline__ float dpp_mv(float x, float idv) {
  int r = __builtin_amdgcn_update_dpp(__float_as_int(idv), __float_as_int(x),
                                      CTRL, RM, 0xf, false);
  return __int_as_float(r);
}
__device__ __forceinline__ float wred_max(float v) {
  v = fmaxf(v, dpp_f<0xB1>(v));                       // xor 1 (quad_perm)
  v = fmaxf(v, dpp_f<0x4E>(v));                       // xor 2 (quad_perm)
  v = fmaxf(v, dpp_f<0x124>(v));                      // row_ror:4
  v = fmaxf(v, dpp_f<0x128>(v));                      // row_ror:8 -> row totals
  v = fmaxf(v, dpp_mv<0x142, 0xa>(v, -1e38f));        // bcast15 -> rows 1,3
  v = fmaxf(v, dpp_mv<0x143, 0xc>(v, -1e38f));        // bcast31 -> rows 2,3
  return __int_as_float(__builtin_amdgcn_readlane(__float_as_int(v), 63));
}
__device__ __forceinline__ float wred_sum(float v) {
  v += dpp_f<0xB1>(v);
  v += dpp_f<0x4E>(v);
  v += dpp_f<0x124>(v);
  v += dpp_f<0x128>(v);
  v += dpp_mv<0x142, 0xa>(v, 0.0f);
  v += dpp_mv<0x143, 0xc>(v, 0.0f);
  return __int_as_float(__builtin_amdgcn_readlane(__float_as_int(v), 63));
}

// ---------------------------------------------------------------- K0: weight folds
__global__ void k0_prep(const float* __restrict__ Wqkv, const float* __restrict__ bqkv,
                        const float* __restrict__ Wmlp, const float* __restrict__ bmlp,
                        float* __restrict__ Wc, float* __restrict__ bc,
                        float* __restrict__ wc2, float* __restrict__ cconst) {
  int t = threadIdx.x;
  int blk = blockIdx.x;
  __shared__ float row_s[E_];
  if (blk < E_) {
    int g = blk;
    row_s[t] = Wqkv[g * 768 + 512 + t];
    __syncthreads();
    int f = t;
    const float4* wm4 = (const float4*)(Wmlp + f * E_);
    const float4* w34 = (const float4*)row_s;
    float acc = 0.f;
#pragma unroll 8
    for (int j = 0; j < E_ / 4; ++j) {
      float4 a = w34[j]; float4 bv = wm4[j];
      acc += a.x * bv.x + a.y * bv.y + a.z * bv.z + a.w * bv.w;
    }
    Wc[g * E_ + f] = acc;
  } else {
    int f = t;
    float a1 = 0.f, a2 = 0.f;
    for (int e = 0; e < E_; ++e) {
      a1 += bqkv[512 + e] * Wmlp[f * E_ + e];
      a2 += Wqkv[f * 768 + 512 + e] * bmlp[e];
    }
    bc[f] = a1;
    wc2[f] = a2;
    if (t == 0) {
      float c = 0.f;
      for (int e = 0; e < E_; ++e) c += bqkv[512 + e] * bmlp[e];
      *cconst = c;
    }
  }
}

// ---------------------------------------------------------------- K1: precompute GEMM (3 tensors, fused halves)
__global__ __launch_bounds__(256, 2)
void k_gemm(const float* __restrict__ emb, const float* __restrict__ Wqkv,
            const float* __restrict__ bqkv,
            const float* __restrict__ Wc, const float* __restrict__ bc,
            float* __restrict__ kk_, float* __restrict__ vv_,
            float* __restrict__ lk2, int ncc, int tmask) {
  __shared__ float As[256 * 64];  // [kk][m], exactly 64 KiB
  int t = threadIdx.x;
  int r0 = blockIdx.x * 64;
  {
    int m = t >> 2;
    int c0 = t & 3;
    const float4* e4 = (const float4*)emb;
#pragma unroll
    for (int p = 0; p < 16; ++p) {
      int c4 = c0 + p * 4;
      float4 a = e4[(size_t)(r0 + m) * 64 + c4];
      As[(c4 * 4 + 0) * 64 + m] = a.x;
      As[(c4 * 4 + 1) * 64 + m] = a.y;
      As[(c4 * 4 + 2) * 64 + m] = a.z;
      As[(c4 * 4 + 3) * 64 + m] = a.w;
    }
  }
  __syncthreads();
  int tx = t & 15, ty = t >> 4;
  const float4* As4 = (const float4*)As;
  for (int cc = 0; cc < ncc; ++cc) {   // cc = tensor index (0:k, 1:v, 2:lk)
    const float* Bp; int ldb4; const float* bias; float* outp;
    switch (cc) {
      case 0:  Bp = Wqkv;       ldb4 = 192; bias = bqkv;       outp = kk_; break;
      case 1:  Bp = Wqkv + 256; ldb4 = 192; bias = bqkv + 256; outp = vv_; break;
      default: Bp = Wc;         ldb4 = 64;  bias = bc;         outp = lk2; break;
    }
    const float4* B4 = (const float4*)Bp;
    // acc[hc][i][jp]: components = scalar cols hc*128 + tx*8 + 2*jp + 0/1.
    // Same per-output fma sequence over kk as R17 -> bit-identical.
    v2f acc[2][4][4];
#pragma unroll
    for (int hc = 0; hc < 2; ++hc)
#pragma unroll
      for (int i = 0; i < 4; ++i)
#pragma unroll
        for (int jp = 0; jp < 4; ++jp) acc[hc][i][jp] = (v2f){0.f, 0.f};

#pragma unroll 2
    for (int kk = 0; kk < 256; ++kk) {
      float4 b00 = B4[kk * ldb4 + tx * 2];
      float4 b01 = B4[kk * ldb4 + tx * 2 + 1];
      float4 b10 = B4[kk * ldb4 + 32 + tx * 2];
      float4 b11 = B4[kk * ldb4 + 32 + tx * 2 + 1];
      v2f p00 = {b00.x, b00.y}, p01 = {b00.z, b00.w};
      v2f p02 = {b01.x, b01.y}, p03 = {b01.z, b01.w};
      v2f p10 = {b10.x, b10.y}, p11 = {b10.z, b10.w};
      v2f p12 = {b11.x, b11.y}, p13 = {b11.z, b11.w};
      float4 av = As4[kk * 16 + ty];
      v2f a01 = {av.x, av.y}, a23 = {av.z, av.w};
      // i=0: bl(a01); i=1: bh(a01); i=2: bl(a23); i=3: bh(a23)
      pkfma_bl(acc[0][0][0], a01, p00); pkfma_bl(acc[0][0][1], a01, p01);
      pkfma_bl(acc[0][0][2], a01, p02); pkfma_bl(acc[0][0][3], a01, p03);
      pkfma_bl(acc[1][0][0], a01, p10); pkfma_bl(acc[1][0][1], a01, p11);
      pkfma_bl(acc[1][0][2], a01, p12); pkfma_bl(acc[1][0][3], a01, p13);
      pkfma_bh(acc[0][1][0], a01, p00); pkfma_bh(acc[0][1][1], a01, p01);
      pkfma_bh(acc[0][1][2], a01, p02); pkfma_bh(acc[0][1][3], a01, p03);
      pkfma_bh(acc[1][1][0], a01, p10); pkfma_bh(acc[1][1][1], a01, p11);
      pkfma_bh(acc[1][1][2], a01, p12); pkfma_bh(acc[1][1][3], a01, p13);
      pkfma_bl(acc[0][2][0], a23, p00); pkfma_bl(acc[0][2][1], a23, p01);
      pkfma_bl(acc[0][2][2], a23, p02); pkfma_bl(acc[0][2][3], a23, p03);
      pkfma_bl(acc[1][2][0], a23, p10); pkfma_bl(acc[1][2][1], a23, p11);
      pkfma_bl(acc[1][2][2], a23, p12); pkfma_bl(acc[1][2][3], a23, p13);
      pkfma_bh(acc[0][3][0], a23, p00); pkfma_bh(acc[0][3][1], a23, p01);
      pkfma_bh(acc[0][3][2], a23, p02); pkfma_bh(acc[0][3][3], a23, p03);
      pkfma_bh(acc[1][3][0], a23, p10); pkfma_bh(acc[1][3][1], a23, p11);
      pkfma_bh(acc[1][3][2], a23, p12); pkfma_bh(acc[1][3][3], a23, p13);
    }
    int tr = (tmask >> cc) & 1;
#pragma unroll
    for (int hc = 0; hc < 2; ++hc) {
      int colbase = hc * 128;
      float bj[8];
#pragma unroll
      for (int j = 0; j < 8; ++j) bj[j] = bias ? bias[colbase + tx * 8 + j] : 0.f;
      if (!tr) {
#pragma unroll
        for (int i = 0; i < 4; ++i) {
          int row = r0 + ty * 4 + i;
          float4 o0 = make_float4(acc[hc][i][0][0] + bj[0], acc[hc][i][0][1] + bj[1],
                                  acc[hc][i][1][0] + bj[2], acc[hc][i][1][1] + bj[3]);
          float4 o1 = make_float4(acc[hc][i][2][0] + bj[4], acc[hc][i][2][1] + bj[5],
                                  acc[hc][i][3][0] + bj[6], acc[hc][i][3][1] + bj[7]);
          float4* o4 = (float4*)(outp + (size_t)row * 256 + colbase + tx * 8);
          o4[0] = o0; o4[1] = o1;
        }
      } else {
#pragma unroll
        for (int i = 0; i < 4; ++i) {
          int row = r0 + ty * 4 + i;
          int bb = row >> 7, nn = row & 127;
          float* op = outp + (size_t)bb * 32768 + nn;
#pragma unroll
          for (int j = 0; j < 8; ++j)
            op[(size_t)(colbase + tx * 8 + j) * 128] = acc[hc][i][j >> 1][j & 1] + bj[j];
        }
      }
    }
  }
}

// ---------------------------------------------------------------- K2: qbase per b
__global__ void k_qbase(const float* __restrict__ emb, const float* __restrict__ Wfix,
                        const float* __restrict__ bfix, const float* __restrict__ Wstep,
                        const float* __restrict__ bstep, float* __restrict__ qbase) {
  int b = blockIdx.x, t = threadIdx.x;
  __shared__ float ge[E_], fi[E_];
  const float* eb = emb + (size_t)b * N_ * E_;
  float s = 0.f;
#pragma unroll 8
  for (int n = 0; n < N_; ++n) s += eb[n * E_ + t];
  ge[t] = s * (1.0f / 128.0f);
  fi[t] = eb[t];
  __syncthreads();
  float acc = bfix[t] + bstep[t];
#pragma unroll 4
  for (int g = 0; g < E_; ++g)
    acc += ge[g] * Wfix[g * E_ + t] + fi[g] * Wstep[g * E_ + t];
  qbase[b * E_ + t] = acc;
}

// ---------------------------------------------------------------- K3: c[b,n]
__global__ void k_c(const float* __restrict__ emb, const float* __restrict__ wc2,
                    const float* __restrict__ cconst, float* __restrict__ cvec) {
  __shared__ float w[E_];
  int t = threadIdx.x;
  w[t] = wc2[t];
  __syncthreads();
  int row = blockIdx.x * 256 + t;
  const float4* e4 = (const float4*)(emb + (size_t)row * E_);
  const float4* w4 = (const float4*)w;
  float acc = 0.f;
#pragma unroll 8
  for (int j = 0; j < E_ / 4; ++j) {
    float4 a = e4[j], bv = w4[j];
    acc += a.x * bv.x + a.y * bv.y + a.z * bv.z + a.w * bv.w;
  }
  cvec[row] = acc + *cconst;
}

// ---------------------------------------------------------------- K4: wave-per-head rollout (verbatim R14/R17)
__global__ __attribute__((amdgpu_flat_work_group_size(512, 512), amdgpu_waves_per_eu(2, 2)))
void k_roll(const float* __restrict__ emb, const float* __restrict__ Wstep,
            const float* __restrict__ kT, const float* __restrict__ vv_,
            const float* __restrict__ lkT,
            const float* __restrict__ qbase, const float* __restrict__ cvec,
            float* __restrict__ out) {
  int lt = threadIdx.x;
  int b = blockIdx.x;
  int h = lt >> 6;      // wave = head
  int j = lt & 63;      // lane

  __shared__ float sq_lds[128 * 260];   // 130 KiB (stride 260: store bank spread)
  __shared__ float work[6144];          // 24 KiB overlay: init At/Bs | at_s/ctx_s/zp
  float* at_s  = work;                  // [8][128] wave-private slices
  float* ctx_s = work + 1024;           // [8][32]  wave-private slices
  float* zp    = work + 1280;           // [2][128 rows x stride 12] z partials

  {
    // ---- init: sq_lds[n][e] = qbase[b][e] + emb[b][n] @ Wstep2 ----
    float* At = work;           // [16][128]
    float* Bs = work + 2048;    // [16][256]
    const float4* eb4 = (const float4*)(emb + (size_t)b * 32768);
    const float* W2 = Wstep + 65536;
    int n0 = (lt & 31) * 4;
    int e0 = (lt >> 5) * 16;
    float acc[4][16];
#pragma unroll
    for (int i = 0; i < 4; ++i)
#pragma unroll
      for (int jj = 0; jj < 16; ++jj) acc[i][jj] = 0.f;

    for (int gc = 0; gc < 16; ++gc) {
      {
        int n = lt & 127, q4g = lt >> 7;
        float4 a = eb4[n * 64 + gc * 4 + q4g];
        At[(q4g * 4 + 0) * 128 + n] = a.x;
        At[(q4g * 4 + 1) * 128 + n] = a.y;
        At[(q4g * 4 + 2) * 128 + n] = a.z;
        At[(q4g * 4 + 3) * 128 + n] = a.w;
      }
      {
        const float4* w4 = (const float4*)(W2 + gc * 16 * 256);
        ((float4*)Bs)[lt] = w4[lt];
        ((float4*)Bs)[lt + 512] = w4[lt + 512];
      }
      __syncthreads();
#pragma unroll
      for (int gi = 0; gi < 16; ++gi) {
        float4 a4 = *(const float4*)(At + gi * 128 + n0);
        const float4* bp = (const float4*)(Bs + gi * 256 + e0);
        float4 b0 = bp[0], b1 = bp[1], b2 = bp[2], b3 = bp[3];
        float av[4] = {a4.x, a4.y, a4.z, a4.w};
        float bv[16] = {b0.x, b0.y, b0.z, b0.w, b1.x, b1.y, b1.z, b1.w,
                        b2.x, b2.y, b2.z, b2.w, b3.x, b3.y, b3.z, b3.w};
#pragma unroll
        for (int i = 0; i < 4; ++i)
#pragma unroll
          for (int jj = 0; jj < 16; ++jj) acc[i][jj] += av[i] * bv[jj];
      }
      __syncthreads();
    }
    const float* qb = qbase + (size_t)b * 256;
    float qbr[16];
#pragma unroll
    for (int jj = 0; jj < 16; ++jj) qbr[jj] = qb[e0 + jj];
#pragma unroll
    for (int i = 0; i < 4; ++i)
#pragma unroll
      for (int jj = 0; jj < 16; ++jj)
        sq_lds[(n0 + i) * 260 + e0 + jj] = acc[i][jj] + qbr[jj];
  }
  __syncthreads();
  __builtin_amdgcn_sched_barrier(0);

  // ---- register fills as v2f pairs (coalesced within 32/64-lane groups) ----
  const float* kTb = kT + (size_t)b * 32768;
  const float* vb  = vv_ + (size_t)b * 32768;
  const float* lTb = lkT + (size_t)b * 32768;

  v2f k0p[16], k1p[16];       // k[h][2d..2d+1][j], k[h][..][j+64]
#pragma unroll
  for (int d = 0; d < 16; ++d) {
    k0p[d] = (v2f){kTb[(h * 32 + 2 * d) * 128 + j],      kTb[(h * 32 + 2 * d + 1) * 128 + j]};
    k1p[d] = (v2f){kTb[(h * 32 + 2 * d) * 128 + j + 64], kTb[(h * 32 + 2 * d + 1) * 128 + j + 64]};
    asm("" : "+v"(k0p[d]));
    asm("" : "+v"(k1p[d]));
  }
  int e_own = h * 32 + (j & 31), nh = j >> 5;
  v2f vp[32];                 // v[nh*64+2m..2m+1][e_own]
#pragma unroll
  for (int m = 0; m < 32; ++m) {
    vp[m] = (v2f){vb[(nh * 64 + 2 * m) * 256 + e_own], vb[(nh * 64 + 2 * m + 1) * 256 + e_own]};
    asm("" : "+v"(vp[m]));
  }
  v2f l0p[16], l1p[16];       // lk2[j][h-slice pairs], lk2[j+64][...]
#pragma unroll
  for (int e = 0; e < 16; ++e) {
    l0p[e] = (v2f){lTb[(h * 32 + 2 * e) * 128 + j],      lTb[(h * 32 + 2 * e + 1) * 128 + j]};
    l1p[e] = (v2f){lTb[(h * 32 + 2 * e) * 128 + j + 64], lTb[(h * 32 + 2 * e + 1) * 128 + j + 64]};
    asm("" : "+v"(l0p[e]));
    asm("" : "+v"(l1p[e]));
  }
  float cv_lo = cvec[b * 128 + j];
  float cv_hi = cvec[b * 128 + j + 64];
  int vis_lo = (j == 0) ? 1 : 0, vis_hi = 0;
  int cur = 0;
  float lp = 0.f;
  int rof0 = j * 12;
  int rof1 = rof0 + 768;      // (j+64)*12
  int csw  = h ^ ((j >> 2) & 7);

#pragma unroll 1
  for (int it = 0; it < N_ - 1; ++it) {
    // --- scores (wave-local; q row broadcast-read from sq_lds) ---
    const float4* q4 = (const float4*)(sq_lds + cur * 260 + h * 32);
    v2f s00 = {0.f, 0.f}, s01 = {0.f, 0.f}, s10 = {0.f, 0.f}, s11 = {0.f, 0.f};
#pragma unroll
    for (int dd = 0; dd < 8; ++dd) {
      float4 qv = q4[dd];
      v2f qa = {qv.x, qv.y}, qb = {qv.z, qv.w};
      pkfma(s00, qa, k0p[2 * dd]);
      pkfma(s01, qb, k0p[2 * dd + 1]);
      pkfma(s10, qa, k1p[2 * dd]);
      pkfma(s11, qb, k1p[2 * dd + 1]);
    }
    float slo = vis_lo ? NEG : ((s00.x + s00.y) + (s01.x + s01.y)) * SCALE;
    float shi = vis_hi ? NEG : ((s10.x + s10.y) + (s11.x + s11.y)) * SCALE;
    // --- softmax (in-wave; division deferred; DPP-only reductions) ---
    float m = wred_max(fmaxf(slo, shi));
    float elo = expf(slo - m), ehi = expf(shi - m);
    at_s[h * 128 + j] = elo;
    at_s[h * 128 + 64 + j] = ehi;
    float inv = 1.0f / wred_sum(elo + ehi);
    // --- ctx for e_own over n-half (wave-local LDS read, no barrier) ---
    const float4* a4 = (const float4*)(at_s + h * 128 + nh * 64);
    v2f c0 = {0.f, 0.f}, c1 = {0.f, 0.f};
#pragma unroll
    for (int mm = 0; mm < 16; ++mm) {
      float4 av = a4[mm];
      v2f aa = {av.x, av.y}, ab = {av.z, av.w};
      pkfma(c0, aa, vp[2 * mm]);
      pkfma(c1, ab, vp[2 * mm + 1]);
    }
    float c = (c0.x + c0.y) + (c1.x + c1.y);
    c += __shfl_xor(c, 32);     // combine n-halves (lanes j, j^32 share e_own)
    c *= inv;
    if (j < 32) ctx_s[h * 32 + j] = c;
    // --- z partial for head-slice (wave-local broadcast read) ---
    const float4* cx4 = (const float4*)(ctx_s + h * 32);
    v2f z00 = {0.f, 0.f}, z01 = {0.f, 0.f}, z10 = {0.f, 0.f}, z11 = {0.f, 0.f};
#pragma unroll
    for (int ee = 0; ee < 8; ++ee) {
      float4 cv = cx4[ee];
      v2f ca = {cv.x, cv.y}, cb = {cv.z, cv.w};
      pkfma(z00, ca, l0p[2 * ee]);
      pkfma(z01, cb, l0p[2 * ee + 1]);
      pkfma(z10, ca, l1p[2 * ee]);
      pkfma(z11, cb, l1p[2 * ee + 1]);
    }
    float* zpw = zp + (it & 1) * 1536;
    zpw[rof0 + csw] = (z00.x + z00.y) + (z01.x + z01.y);
    zpw[rof1 + csw] = (z10.x + z10.y) + (z11.x + z11.y);
    __syncthreads();   // the ONLY barrier per step

    // --- phase C: assemble z via 2x b128/half + argmax; LSE wave 0 only ---
    const float4* zr0 = (const float4*)(zpw + rof0);
    const float4* zr1 = (const float4*)(zpw + rof1);
    float4 za = zr0[0], zb = zr0[1], zc = zr1[0], zd = zr1[1];
    float zlo = cv_lo + ((za.x + za.y) + (za.z + za.w)) + ((zb.x + zb.y) + (zb.z + zb.w));
    float zhi = cv_hi + ((zc.x + zc.y) + (zc.z + zc.w)) + ((zd.x + zd.y) + (zd.z + zd.w));
    float zmlo = vis_lo ? -1e30f : zlo;
    float zmhi = vis_hi ? -1e30f : zhi;
    float vmax = wred_max(fmaxf(zmlo, zmhi));
    unsigned long long blo = __ballot(zmlo == vmax);
    int action;
    if (blo) action = __ffsll((unsigned long long)blo) - 1;
    else     action = 63 + __ffsll((unsigned long long)__ballot(zmhi == vmax));
    if (h == 0) {
      float lmax = CLIPV * tanhf(vmax * SCALE);
      float tlo = vis_lo ? 0.f : expf(CLIPV * tanhf(zlo * SCALE) - 10.0f);
      float thi = vis_hi ? 0.f : expf(CLIPV * tanhf(zhi * SCALE) - 10.0f);
      float S = wred_sum(tlo + thi);
      lp += lmax - 10.0f - logf(S);
    }
    cur = action;
    vis_lo |= (action == j);
    vis_hi |= (action == j + 64);
  }
  if (lt == 0) out[b] = lp;
}

// ---------------------------------------------------------------- launch
extern "C" void kernel_launch(void* const* d_in, const int* in_sizes, int n_in,
                              void* d_out, int out_size, void* d_ws, size_t ws_size,
                              hipStream_t stream) {
  (void)in_sizes; (void)n_in; (void)out_size; (void)ws_size;
  const float* emb   = (const float*)d_in[0];
  const float* Wqkv  = (const float*)d_in[1];
  const float* bqkv  = (const float*)d_in[2];
  const float* Wfix  = (const float*)d_in[3];
  const float* bfix  = (const float*)d_in[4];
  const float* Wstep = (const float*)d_in[5];
  const float* bstep = (const float*)d_in[6];
  const float* Wmlp  = (const float*)d_in[7];
  const float* bmlp  = (const float*)d_in[8];
  float* out = (float*)d_out;
  float* ws = (float*)d_ws;

  const size_t NBE = (size_t)B_ * N_ * E_;  // 16,777,216 floats
  float* kk_    = ws;                  // kT
  float* vv_    = ws + NBE;            // v
  float* lk2    = ws + 2 * NBE;        // lkT
  float* qbase  = ws + 3 * NBE;        // 131072
  float* cvec   = qbase + 131072;      // 65536
  float* Wc     = cvec + 65536;        // 65536
  float* bc     = Wc + 65536;          // 256
  float* wc2    = bc + 256;            // 256
  float* cconst = wc2 + 256;           // (64 pad)

  hipLaunchKernelGGL(k0_prep, dim3(257), dim3(256), 0, stream,
                     Wqkv, bqkv, Wmlp, bmlp, Wc, bc, wc2, cconst);
  hipLaunchKernelGGL(k_qbase, dim3(512), dim3(256), 0, stream,
                     emb, Wfix, bfix, Wstep, bstep, qbase);
  hipLaunchKernelGGL(k_c, dim3(256), dim3(256), 0, stream,
                     emb, wc2, cconst, cvec);
  hipLaunchKernelGGL(k_gemm, dim3(1024), dim3(256), 0, stream,
                     emb, Wqkv, bqkv, Wc, bc, kk_, vv_, lk2, 3, 0b101);
  hipLaunchKernelGGL(k_roll, dim3(512), dim3(512), 0, stream,
                     emb, Wstep, kk_, vv_, lk2, qbase, cvec, out);
}